// Round 3
// baseline (110.618 us; speedup 1.0000x reference)
//
#include <hip/hip_runtime.h>
#include <hip/hip_bf16.h>

#define BN 4096
#define DD 128
#define NTILES 8   // 8 tiles x 64 cols = 512-col chunk per block

typedef __bf16 bf16x8 __attribute__((ext_vector_type(8)));
typedef float f32x16 __attribute__((ext_vector_type(16)));

__device__ __forceinline__ void gload_lds16(const void* g, void* l) {
    __builtin_amdgcn_global_load_lds(
        (const __attribute__((address_space(1))) void*)g,
        (__attribute__((address_space(3))) void*)l, 16, 0, 0);
}

// ---------------- prep: f32 -> bf16 (with gather), diag dots, zero accums ----
__global__ __launch_bounds__(64) void prep_kernel(
    const float* __restrict__ z1, const float* __restrict__ z2,
    const float* __restrict__ attr, const int* __restrict__ uni,
    __hip_bfloat16* __restrict__ Z1b, __hip_bfloat16* __restrict__ Z2b,
    __hip_bfloat16* __restrict__ G1b, __hip_bfloat16* __restrict__ G2b,
    __hip_bfloat16* __restrict__ Ab,
    float* __restrict__ d1, float* __restrict__ d2, float* __restrict__ d3,
    float* __restrict__ S1, float* __restrict__ S2, float* __restrict__ out)
{
    int r = blockIdx.x;
    int t = threadIdx.x;
    int gid = r * 64 + t;
    if (gid < 4 * BN) { S1[gid] = 0.f; S2[gid] = 0.f; }
    if (gid == 0) out[0] = 0.f;

    int au = uni[r];
    float p1 = 0.f, p2 = 0.f, p3 = 0.f;
    #pragma unroll
    for (int e = t; e < DD; e += 64) {
        float v1 = z1[(size_t)r * DD + e];
        float v2 = z2[(size_t)r * DD + e];
        float ga = attr[(size_t)au * DD + e];
        float g1 = z1[(size_t)au * DD + e];
        float g2 = z2[(size_t)au * DD + e];
        Z1b[(size_t)r * DD + e] = __float2bfloat16(v1);
        Z2b[(size_t)r * DD + e] = __float2bfloat16(v2);
        G1b[(size_t)r * DD + e] = __float2bfloat16(g1);
        G2b[(size_t)r * DD + e] = __float2bfloat16(g2);
        Ab [(size_t)r * DD + e] = __float2bfloat16(ga);
        p1 += g1 * ga; p2 += g2 * ga; p3 += v1 * v2;
    }
    #pragma unroll
    for (int m = 1; m < 64; m <<= 1) {
        p1 += __shfl_xor(p1, m);
        p2 += __shfl_xor(p2, m);
        p3 += __shfl_xor(p3, m);
    }
    if (t == 0) { d1[r] = p1; d2[r] = p2; d3[r] = p3; }
}

// ---------------- rowsum: fused sim + exp row-sum over 4 jobs ----------------
// job 0: X=G1b vs Y=Ab        (4096 cols)  chunks  0..7
// job 1: X=G2b vs Y=Ab        (4096 cols)  chunks  8..15
// job 2: X=Z1b vs Y={Z1b,Z2b} (8192 cols)  chunks 16..31
// job 3: X=Z2b vs Y={Z1b,Z2b} (8192 cols)  chunks 32..47
// Block: 4 waves x 32 X-rows = 128 rows; Y staged in fragment-order LDS:
// granule (G*512 + s*64 + lane) holds Y[tile + G*32 + (lane&31)] bytes
// [16*(2s+(lane>>5)) .. +16) -> ds_read_b128 at lane*16 + imm, conflict-free.
__global__ __launch_bounds__(256, 5) void rowsum_kernel(
    const __hip_bfloat16* __restrict__ Z1b, const __hip_bfloat16* __restrict__ Z2b,
    const __hip_bfloat16* __restrict__ G1b, const __hip_bfloat16* __restrict__ G2b,
    const __hip_bfloat16* __restrict__ Ab,
    float* __restrict__ S1, float* __restrict__ S2)
{
    int rowblk = blockIdx.x;   // 0..31 : 128 X-rows each
    int chunk  = blockIdx.y;   // 0..47 : 512 Y-rows each

    int job;
    const __hip_bfloat16 *X, *Y;
    int ybase;
    if (chunk < 8)       { job = 0; X = G1b; Y = Ab; ybase = chunk * 512; }
    else if (chunk < 16) { job = 1; X = G2b; Y = Ab; ybase = (chunk - 8) * 512; }
    else if (chunk < 32) { job = 2; X = Z1b; ybase = (chunk - 16) * 512;
                           Y = (ybase < BN) ? Z1b : Z2b; if (ybase >= BN) ybase -= BN; }
    else                 { job = 3; X = Z2b; ybase = (chunk - 32) * 512;
                           Y = (ybase < BN) ? Z1b : Z2b; if (ybase >= BN) ybase -= BN; }

    __shared__ char lds[2 * 16384];   // double-buffered 64-row Y tiles

    int tid  = threadIdx.x;
    int wid  = tid >> 6;      // 0..3
    int lane = tid & 63;
    int r = lane & 31, h = lane >> 5;

    // A fragments (v_mfma_f32_32x32x16_bf16): row = lane&31, k = 16s + 8h + j
    int xrow0 = rowblk * 128 + wid * 32;
    const __hip_bfloat16* xrow = X + (size_t)(xrow0 + r) * DD + 8 * h;
    bf16x8 afrag[8];
    #pragma unroll
    for (int s = 0; s < 8; s++)
        afrag[s] = *reinterpret_cast<const bf16x8*>(xrow + 16 * s);

    // Staging: dest granule g (linear, 4 per thread) -> source fragment addr.
    int soff[4];
    #pragma unroll
    for (int i = 0; i < 4; i++) {
        int g = wid * 256 + i * 64 + lane;
        int G = g >> 9, s = (g >> 6) & 7, l = g & 63;
        int rr = G * 32 + (l & 31);
        int cg = 2 * s + (l >> 5);
        soff[i] = rr * 256 + cg * 16;
    }
    const char* Ychunk = (const char*)Y + (size_t)ybase * 256;

    float acc1[16], acc2[16];
    #pragma unroll
    for (int q = 0; q < 16; q++) { acc1[q] = 0.f; acc2[q] = 0.f; }

    auto stage = [&](int b, int ct) {
        const char* gsrc = Ychunk + (size_t)ct * 16384;
        #pragma unroll
        for (int i = 0; i < 4; i++)
            gload_lds16(gsrc + soff[i], lds + b * 16384 + ((wid * 256 + i * 64) << 4));
    };

    const char* rbase = lds + lane * 16;

    stage(0, 0);
    __syncthreads();
    int cur = 0;
    for (int ct = 0; ct < NTILES; ct++) {
        if (ct + 1 < NTILES) stage(cur ^ 1, ct + 1);   // prefetch next tile
        const char* tb = rbase + cur * 16384;
        #pragma unroll
        for (int G = 0; G < 2; G++) {                  // two 32-col groups
            f32x16 cacc;
            #pragma unroll
            for (int q = 0; q < 16; q++) cacc[q] = 0.f;
            #pragma unroll
            for (int s = 0; s < 8; s++) {
                bf16x8 bfrag = *reinterpret_cast<const bf16x8*>(tb + G * 8192 + s * 1024);
                cacc = __builtin_amdgcn_mfma_f32_32x32x16_bf16(afrag[s], bfrag, cacc, 0, 0, 0);
            }
            // sim = dot/TEMP = 2*dot ; e1 = exp(sim); e1^2 = exp(2*sim)
            #pragma unroll
            for (int q = 0; q < 16; q++) {
                float e1 = __expf(2.0f * cacc[q]);
                acc1[q] += e1;
                acc2[q] = fmaf(e1, e1, acc2[q]);
            }
        }
        __syncthreads();
        cur ^= 1;
    }

    // Reduce over the 32 lanes sharing each output row
    #pragma unroll
    for (int q = 0; q < 16; q++) {
        float a1 = acc1[q], a2 = acc2[q];
        #pragma unroll
        for (int m = 1; m < 32; m <<= 1) {
            a1 += __shfl_xor(a1, m);
            a2 += __shfl_xor(a2, m);
        }
        acc1[q] = a1; acc2[q] = a2;
    }
    if (r == 0) {
        // C/D layout: col = lane&31, row = (q&3) + 8*(q>>2) + 4*(lane>>5)
        #pragma unroll
        for (int q = 0; q < 16; q++) {
            int grow = xrow0 + (q & 3) + 8 * (q >> 2) + 4 * h;
            atomicAdd(&S1[job * BN + grow], acc1[q]);
            atomicAdd(&S2[job * BN + grow], acc2[q]);
        }
    }
}

// ---------------- finalize: per-row loss terms -> weighted mean --------------
__global__ __launch_bounds__(256) void finalize_kernel(
    const float* __restrict__ S1, const float* __restrict__ S2,
    const float* __restrict__ d1, const float* __restrict__ d2,
    const float* __restrict__ d3, float* __restrict__ out)
{
    int idx = blockIdx.x * 256 + threadIdx.x;   // 0..16383
    float term = 0.f;
    const float EM2 = 0.13533528323661270f;     // e^-2
    if (idx < 8192) {                           // inter jobs 0/1
        int j = idx >> 12, i = idx & 4095;
        float dv = j ? d2[i] : d1[i];
        float n = 4095.f;
        float pos = __expf(2.f * dv);
        float s1 = S1[j * BN + i] - pos;
        float s2 = S2[j * BN + i] - pos * pos;
        float rw = s2 * n / s1;
        float ng = (-0.1f * n * pos + rw) * (1.f / 0.9f);
        ng = fmaxf(ng, n * EM2);
        term = logf((pos + ng) / pos) * (0.5f / 4096.f);
    } else {                                    // intra rows 0..8191
        int i = idx - 8192;
        int ii = i & 4095;
        int job = 2 + (i >> 12);
        float n = 8190.f;
        const float E2 = 7.3890560989306495f, E4 = 54.598150033144236f;
        float pos = __expf(2.f * d3[ii]);
        float s1 = S1[job * BN + ii] - E2 - pos;
        float s2 = S2[job * BN + ii] - E4 - pos * pos;
        float rw = s2 * n / s1;
        float ng = (-0.1f * n * pos + rw) * (1.f / 0.9f);
        ng = fmaxf(ng, n * EM2);
        term = logf((pos + ng) / pos) * (1.f / 8192.f);
    }

    #pragma unroll
    for (int m = 1; m < 64; m <<= 1) term += __shfl_xor(term, m);
    __shared__ float sm[4];
    int wid = threadIdx.x >> 6;
    if ((threadIdx.x & 63) == 0) sm[wid] = term;
    __syncthreads();
    if (threadIdx.x == 0) atomicAdd(out, sm[0] + sm[1] + sm[2] + sm[3]);
}

extern "C" void kernel_launch(void* const* d_in, const int* in_sizes, int n_in,
                              void* d_out, int out_size, void* d_ws, size_t ws_size,
                              hipStream_t stream)
{
    const float* z1   = (const float*)d_in[0];
    const float* z2   = (const float*)d_in[1];
    // d_in[2] = text_z : unused by the reference
    const float* attr = (const float*)d_in[3];
    const int*   uni  = (const int*)d_in[4];
    float* out = (float*)d_out;

    char* ws = (char*)d_ws;
    size_t mat = (size_t)BN * DD;                    // elements per matrix
    __hip_bfloat16* Z1b = (__hip_bfloat16*)ws;
    __hip_bfloat16* Z2b = Z1b + mat;
    __hip_bfloat16* G1b = Z2b + mat;
    __hip_bfloat16* G2b = G1b + mat;
    __hip_bfloat16* Ab  = G2b + mat;
    float* S1 = (float*)(ws + 5 * mat * sizeof(__hip_bfloat16));
    float* S2 = S1 + 4 * BN;
    float* d1 = S2 + 4 * BN;
    float* d2 = d1 + BN;
    float* d3 = d2 + BN;

    prep_kernel<<<BN, 64, 0, stream>>>(z1, z2, attr, uni,
                                       Z1b, Z2b, G1b, G2b, Ab,
                                       d1, d2, d3, S1, S2, out);
    rowsum_kernel<<<dim3(32, 48), 256, 0, stream>>>(Z1b, Z2b, G1b, G2b, Ab, S1, S2);
    finalize_kernel<<<64, 256, 0, stream>>>(S1, S2, d1, d2, d3, out);
}

// Round 4
// 90.749 us; speedup vs baseline: 1.2189x; 1.2189x over previous
//
#include <hip/hip_runtime.h>
#include <hip/hip_bf16.h>

#define BN 4096
#define DD 128
#define NTILES 8   // 8 tiles x 64 cols = 512-col chunk per block

typedef __bf16 bf16x8 __attribute__((ext_vector_type(8)));
typedef float f32x16 __attribute__((ext_vector_type(16)));

__device__ __forceinline__ void gload_lds16(const void* g, void* l) {
    __builtin_amdgcn_global_load_lds(
        (const __attribute__((address_space(1))) void*)g,
        (__attribute__((address_space(3))) void*)l, 16, 0, 0);
}

// ---------------- prep: f32 -> bf16 fragment-major (+gather), diag dots -----
// Fragment-major: per 32-row panel (8192 B), granule g = s*64 + h*32 + r
// holds row r, elements [16s+8h, 16s+8h+8). This makes BOTH the rowsum
// staging source (identity/linear) and the ds_read (lane*16 + imm) trivial.
__global__ __launch_bounds__(256) void prep_kernel(
    const float* __restrict__ z1, const float* __restrict__ z2,
    const float* __restrict__ attr, const int* __restrict__ uni,
    char* __restrict__ Z1f, char* __restrict__ Z2f,
    char* __restrict__ G1f, char* __restrict__ G2f, char* __restrict__ Af,
    float* __restrict__ d1, float* __restrict__ d2, float* __restrict__ d3,
    float* __restrict__ S1, float* __restrict__ S2, float* __restrict__ out)
{
    int p = blockIdx.x;        // panel 0..127
    int t = threadIdx.x;       // 0..255
    int gid = p * 256 + t;
    if (gid < 4 * BN) { S1[gid] = 0.f; S2[gid] = 0.f; }
    if (gid == 0) out[0] = 0.f;

    int r = t >> 3, q = t & 7;         // row-in-panel, col-quarter(16 f32)
    int grow = p * 32 + r;
    int arow = uni[grow];

    __shared__ __hip_bfloat16 lp[5][32][128];

    const float* sp[5] = { z1 + (size_t)grow * DD, z2 + (size_t)grow * DD,
                           z1 + (size_t)arow * DD, z2 + (size_t)arow * DD,
                           attr + (size_t)arow * DD };
    float v[5][16];
    #pragma unroll
    for (int m = 0; m < 5; m++) {
        const float4* s4 = (const float4*)(sp[m] + q * 16);
        #pragma unroll
        for (int i = 0; i < 4; i++) {
            float4 f = s4[i];
            v[m][4*i+0] = f.x; v[m][4*i+1] = f.y;
            v[m][4*i+2] = f.z; v[m][4*i+3] = f.w;
        }
    }
    float p1 = 0.f, p2 = 0.f, p3 = 0.f;
    #pragma unroll
    for (int e = 0; e < 16; e++) {
        p3 += v[0][e] * v[1][e];
        p1 += v[2][e] * v[4][e];
        p2 += v[3][e] * v[4][e];
    }
    #pragma unroll
    for (int m = 1; m < 8; m <<= 1) {
        p1 += __shfl_xor(p1, m);
        p2 += __shfl_xor(p2, m);
        p3 += __shfl_xor(p3, m);
    }
    if (q == 0) { d1[grow] = p1; d2[grow] = p2; d3[grow] = p3; }

    #pragma unroll
    for (int m = 0; m < 5; m++)
        #pragma unroll
        for (int e = 0; e < 16; e++)
            lp[m][r][q * 16 + e] = __float2bfloat16(v[m][e]);
    __syncthreads();

    char* dsts[5] = { Z1f, Z2f, G1f, G2f, Af };
    #pragma unroll
    for (int m = 0; m < 5; m++) {
        #pragma unroll
        for (int j = 0; j < 2; j++) {
            int g = t + 256 * j;                 // granule 0..511
            int s = g >> 6, h = (g >> 5) & 1, rr = g & 31;
            bf16x8 val = *reinterpret_cast<const bf16x8*>(&lp[m][rr][s * 16 + h * 8]);
            *reinterpret_cast<bf16x8*>(dsts[m] + (size_t)p * 8192 + (size_t)g * 16) = val;
        }
    }
}

// ---------------- rowsum: fused sim + exp row-sum over 4 jobs ----------------
// job 0: X=G1f vs Y=Af        chunks  0..7
// job 1: X=G2f vs Y=Af        chunks  8..15
// job 2: X=Z1f vs Y={Z1f,Z2f} chunks 16..31
// job 3: X=Z2f vs Y={Z1f,Z2f} chunks 32..47
// All buffers fragment-major. Staging: identity offsets (coalesced 1KB/inst).
// Reads: ds_read_b128 at lane*16 + imm (conflict-free, no addr VALU).
__global__ __launch_bounds__(256, 5) void rowsum_kernel(
    const char* __restrict__ Z1f, const char* __restrict__ Z2f,
    const char* __restrict__ G1f, const char* __restrict__ G2f,
    const char* __restrict__ Af,
    float* __restrict__ S1, float* __restrict__ S2)
{
    int rowblk = blockIdx.x;   // 0..31 : 128 X-rows each
    int chunk  = blockIdx.y;   // 0..47 : 512 Y-rows each

    int job;
    const char *X, *Y;
    int ybase;
    if (chunk < 8)       { job = 0; X = G1f; Y = Af; ybase = chunk * 512; }
    else if (chunk < 16) { job = 1; X = G2f; Y = Af; ybase = (chunk - 8) * 512; }
    else if (chunk < 32) { job = 2; X = Z1f; ybase = (chunk - 16) * 512;
                           Y = (ybase < BN) ? Z1f : Z2f; if (ybase >= BN) ybase -= BN; }
    else                 { job = 3; X = Z2f; ybase = (chunk - 32) * 512;
                           Y = (ybase < BN) ? Z1f : Z2f; if (ybase >= BN) ybase -= BN; }

    __shared__ char lds[2 * 16384];   // double-buffered 64-row Y tiles

    int tid  = threadIdx.x;
    int wid  = tid >> 6;      // 0..3
    int lane = tid & 63;
    int r = lane & 31, h = lane >> 5;

    // A fragments from fragment-major X: panel px, addr s*1024 + h*512 + r*16
    int xrow0 = rowblk * 128 + wid * 32;
    int px = rowblk * 4 + wid;
    const char* xp = X + (size_t)px * 8192 + h * 512 + r * 16;
    bf16x8 afrag[8];
    #pragma unroll
    for (int s = 0; s < 8; s++)
        afrag[s] = *reinterpret_cast<const bf16x8*>(xp + s * 1024);

    const char* Ychunk = Y + (size_t)ybase * 256;   // panel-aligned (512 rows)

    float acc1[16], acc2[16];
    #pragma unroll
    for (int q = 0; q < 16; q++) { acc1[q] = 0.f; acc2[q] = 0.f; }

    auto stage = [&](int b, int ct) {
        const char* gsrc = Ychunk + (size_t)ct * 16384;
        #pragma unroll
        for (int i = 0; i < 4; i++)
            gload_lds16(gsrc + wid * 4096 + i * 1024 + lane * 16,
                        lds + b * 16384 + ((wid * 256 + i * 64) << 4));
    };

    const char* rbase = lds + lane * 16;

    stage(0, 0);
    __syncthreads();
    int cur = 0;
    for (int ct = 0; ct < NTILES; ct++) {
        if (ct + 1 < NTILES) stage(cur ^ 1, ct + 1);   // prefetch next tile
        const char* tb = rbase + cur * 16384;
        #pragma unroll
        for (int G = 0; G < 2; G++) {                  // two 32-col groups
            f32x16 cacc;
            #pragma unroll
            for (int q = 0; q < 16; q++) cacc[q] = 0.f;
            #pragma unroll
            for (int s = 0; s < 8; s++) {
                bf16x8 bfrag = *reinterpret_cast<const bf16x8*>(tb + G * 8192 + s * 1024);
                cacc = __builtin_amdgcn_mfma_f32_32x32x16_bf16(afrag[s], bfrag, cacc, 0, 0, 0);
            }
            // sim = dot/TEMP = 2*dot ; e1 = exp(sim); e1^2 = exp(2*sim)
            #pragma unroll
            for (int q = 0; q < 16; q++) {
                float e1 = __expf(2.0f * cacc[q]);
                acc1[q] += e1;
                acc2[q] = fmaf(e1, e1, acc2[q]);
            }
        }
        __syncthreads();
        cur ^= 1;
    }

    // Reduce over the 32 lanes sharing each output row
    #pragma unroll
    for (int q = 0; q < 16; q++) {
        float a1 = acc1[q], a2 = acc2[q];
        #pragma unroll
        for (int m = 1; m < 32; m <<= 1) {
            a1 += __shfl_xor(a1, m);
            a2 += __shfl_xor(a2, m);
        }
        acc1[q] = a1; acc2[q] = a2;
    }
    if (r == 0) {
        // C/D layout: col = lane&31, row = (q&3) + 8*(q>>2) + 4*(lane>>5)
        #pragma unroll
        for (int q = 0; q < 16; q++) {
            int grow = xrow0 + (q & 3) + 8 * (q >> 2) + 4 * h;
            atomicAdd(&S1[job * BN + grow], acc1[q]);
            atomicAdd(&S2[job * BN + grow], acc2[q]);
        }
    }
}

// ---------------- finalize: per-row loss terms -> weighted mean --------------
__global__ __launch_bounds__(256) void finalize_kernel(
    const float* __restrict__ S1, const float* __restrict__ S2,
    const float* __restrict__ d1, const float* __restrict__ d2,
    const float* __restrict__ d3, float* __restrict__ out)
{
    int idx = blockIdx.x * 256 + threadIdx.x;   // 0..16383
    float term = 0.f;
    const float EM2 = 0.13533528323661270f;     // e^-2
    if (idx < 8192) {                           // inter jobs 0/1
        int j = idx >> 12, i = idx & 4095;
        float dv = j ? d2[i] : d1[i];
        float n = 4095.f;
        float pos = __expf(2.f * dv);
        float s1 = S1[j * BN + i] - pos;
        float s2 = S2[j * BN + i] - pos * pos;
        float rw = s2 * n / s1;
        float ng = (-0.1f * n * pos + rw) * (1.f / 0.9f);
        ng = fmaxf(ng, n * EM2);
        term = logf((pos + ng) / pos) * (0.5f / 4096.f);
    } else {                                    // intra rows 0..8191
        int i = idx - 8192;
        int ii = i & 4095;
        int job = 2 + (i >> 12);
        float n = 8190.f;
        const float E2 = 7.3890560989306495f, E4 = 54.598150033144236f;
        float pos = __expf(2.f * d3[ii]);
        float s1 = S1[job * BN + ii] - E2 - pos;
        float s2 = S2[job * BN + ii] - E4 - pos * pos;
        float rw = s2 * n / s1;
        float ng = (-0.1f * n * pos + rw) * (1.f / 0.9f);
        ng = fmaxf(ng, n * EM2);
        term = logf((pos + ng) / pos) * (1.f / 8192.f);
    }

    #pragma unroll
    for (int m = 1; m < 64; m <<= 1) term += __shfl_xor(term, m);
    __shared__ float sm[4];
    int wid = threadIdx.x >> 6;
    if ((threadIdx.x & 63) == 0) sm[wid] = term;
    __syncthreads();
    if (threadIdx.x == 0) atomicAdd(out, sm[0] + sm[1] + sm[2] + sm[3]);
}

extern "C" void kernel_launch(void* const* d_in, const int* in_sizes, int n_in,
                              void* d_out, int out_size, void* d_ws, size_t ws_size,
                              hipStream_t stream)
{
    const float* z1   = (const float*)d_in[0];
    const float* z2   = (const float*)d_in[1];
    // d_in[2] = text_z : unused by the reference
    const float* attr = (const float*)d_in[3];
    const int*   uni  = (const int*)d_in[4];
    float* out = (float*)d_out;

    char* ws = (char*)d_ws;
    size_t matb = (size_t)BN * DD * 2;               // bytes per bf16 matrix
    char* Z1f = ws;
    char* Z2f = Z1f + matb;
    char* G1f = Z2f + matb;
    char* G2f = G1f + matb;
    char* Af  = G2f + matb;
    float* S1 = (float*)(ws + 5 * matb);
    float* S2 = S1 + 4 * BN;
    float* d1 = S2 + 4 * BN;
    float* d2 = d1 + BN;
    float* d3 = d2 + BN;

    prep_kernel<<<128, 256, 0, stream>>>(z1, z2, attr, uni,
                                         Z1f, Z2f, G1f, G2f, Af,
                                         d1, d2, d3, S1, S2, out);
    rowsum_kernel<<<dim3(32, 48), 256, 0, stream>>>(Z1f, Z2f, G1f, G2f, Af, S1, S2);
    finalize_kernel<<<64, 256, 0, stream>>>(S1, S2, d1, d2, d3, out);
}

// Round 5
// 52.315 us; speedup vs baseline: 2.1145x; 1.7347x over previous
//
#include <hip/hip_runtime.h>
#include <hip/hip_bf16.h>

#define BN 4096
#define DD 128
#define NTILES 16   // 16 tiles x 64 cols = 1024-col chunk per block

typedef __bf16 bf16x8 __attribute__((ext_vector_type(8)));
typedef float f32x16 __attribute__((ext_vector_type(16)));

__device__ __forceinline__ void gload_lds16(const void* g, void* l) {
    __builtin_amdgcn_global_load_lds(
        (const __attribute__((address_space(1))) void*)g,
        (__attribute__((address_space(3))) void*)l, 16, 0, 0);
}

// ---------------- prep: f32 -> bf16 fragment-major (+gather), diag dots -----
// Fragment-major: per 32-row panel (8192 B), granule g = s*64 + h*32 + r
// holds row r, elements [16s+8h, 16s+8h+8). This makes BOTH the rowsum
// staging source (identity/linear) and the ds_read (lane*16 + imm) trivial.
__global__ __launch_bounds__(256) void prep_kernel(
    const float* __restrict__ z1, const float* __restrict__ z2,
    const float* __restrict__ attr, const int* __restrict__ uni,
    char* __restrict__ Z1f, char* __restrict__ Z2f,
    char* __restrict__ G1f, char* __restrict__ G2f, char* __restrict__ Af,
    float* __restrict__ d1, float* __restrict__ d2, float* __restrict__ d3,
    float* __restrict__ S1, float* __restrict__ S2, float* __restrict__ out)
{
    int p = blockIdx.x;        // panel 0..127
    int t = threadIdx.x;       // 0..255
    int gid = p * 256 + t;
    if (gid < 4 * BN) { S1[gid] = 0.f; S2[gid] = 0.f; }
    if (gid == 0) out[0] = 0.f;

    int r = t >> 3, q = t & 7;         // row-in-panel, col-quarter(16 f32)
    int grow = p * 32 + r;
    int arow = uni[grow];

    __shared__ __hip_bfloat16 lp[5][32][128];

    const float* sp[5] = { z1 + (size_t)grow * DD, z2 + (size_t)grow * DD,
                           z1 + (size_t)arow * DD, z2 + (size_t)arow * DD,
                           attr + (size_t)arow * DD };
    float v[5][16];
    #pragma unroll
    for (int m = 0; m < 5; m++) {
        const float4* s4 = (const float4*)(sp[m] + q * 16);
        #pragma unroll
        for (int i = 0; i < 4; i++) {
            float4 f = s4[i];
            v[m][4*i+0] = f.x; v[m][4*i+1] = f.y;
            v[m][4*i+2] = f.z; v[m][4*i+3] = f.w;
        }
    }
    float p1 = 0.f, p2 = 0.f, p3 = 0.f;
    #pragma unroll
    for (int e = 0; e < 16; e++) {
        p3 += v[0][e] * v[1][e];
        p1 += v[2][e] * v[4][e];
        p2 += v[3][e] * v[4][e];
    }
    #pragma unroll
    for (int m = 1; m < 8; m <<= 1) {
        p1 += __shfl_xor(p1, m);
        p2 += __shfl_xor(p2, m);
        p3 += __shfl_xor(p3, m);
    }
    if (q == 0) { d1[grow] = p1; d2[grow] = p2; d3[grow] = p3; }

    #pragma unroll
    for (int m = 0; m < 5; m++)
        #pragma unroll
        for (int e = 0; e < 16; e++)
            lp[m][r][q * 16 + e] = __float2bfloat16(v[m][e]);
    __syncthreads();

    char* dsts[5] = { Z1f, Z2f, G1f, G2f, Af };
    #pragma unroll
    for (int m = 0; m < 5; m++) {
        #pragma unroll
        for (int j = 0; j < 2; j++) {
            int g = t + 256 * j;                 // granule 0..511
            int s = g >> 6, h = (g >> 5) & 1, rr = g & 31;
            bf16x8 val = *reinterpret_cast<const bf16x8*>(&lp[m][rr][s * 16 + h * 8]);
            *reinterpret_cast<bf16x8*>(dsts[m] + (size_t)p * 8192 + (size_t)g * 16) = val;
        }
    }
}

// ---------------- rowsum: fused sim + exp row-sum over 4 jobs ----------------
// job 0: X=G1f vs Y=Af        chunks  0..3
// job 1: X=G2f vs Y=Af        chunks  4..7
// job 2: X=Z1f vs Y={Z1f,Z2f} chunks  8..15
// job 3: X=Z2f vs Y={Z1f,Z2f} chunks 16..23
// All buffers fragment-major. Staging: identity offsets (coalesced 1KB/inst).
// Reads: ds_read_b128 at lane*16 + imm (conflict-free, no addr VALU).
// launch_bounds(256,3): VGPR cap ~170 -- rounds 3/4 showed (256,5) forces
// accumulator spill to scratch (WRITE_SIZE 3->54 MB, 2x slowdown).
__global__ __launch_bounds__(256, 3) void rowsum_kernel(
    const char* __restrict__ Z1f, const char* __restrict__ Z2f,
    const char* __restrict__ G1f, const char* __restrict__ G2f,
    const char* __restrict__ Af,
    float* __restrict__ S1, float* __restrict__ S2)
{
    int rowblk = blockIdx.x;   // 0..31 : 128 X-rows each
    int chunk  = blockIdx.y;   // 0..23 : 1024 Y-rows each

    int job;
    const char *X, *Y;
    int ybase;
    if (chunk < 4)       { job = 0; X = G1f; Y = Af; ybase = chunk * 1024; }
    else if (chunk < 8)  { job = 1; X = G2f; Y = Af; ybase = (chunk - 4) * 1024; }
    else if (chunk < 16) { job = 2; X = Z1f; ybase = (chunk - 8) * 1024;
                           Y = (ybase < BN) ? Z1f : Z2f; if (ybase >= BN) ybase -= BN; }
    else                 { job = 3; X = Z2f; ybase = (chunk - 16) * 1024;
                           Y = (ybase < BN) ? Z1f : Z2f; if (ybase >= BN) ybase -= BN; }

    __shared__ char lds[2 * 16384];   // double-buffered 64-row Y tiles

    int tid  = threadIdx.x;
    int wid  = tid >> 6;      // 0..3
    int lane = tid & 63;
    int r = lane & 31, h = lane >> 5;

    // A fragments from fragment-major X: panel px, addr s*1024 + h*512 + r*16
    int xrow0 = rowblk * 128 + wid * 32;
    int px = rowblk * 4 + wid;
    const char* xp = X + (size_t)px * 8192 + h * 512 + r * 16;
    bf16x8 afrag[8];
    #pragma unroll
    for (int s = 0; s < 8; s++)
        afrag[s] = *reinterpret_cast<const bf16x8*>(xp + s * 1024);

    const char* Ychunk = Y + (size_t)ybase * 256;   // panel-aligned (1024 rows)

    float acc1[16], acc2[16];
    #pragma unroll
    for (int q = 0; q < 16; q++) { acc1[q] = 0.f; acc2[q] = 0.f; }

    auto stage = [&](int b, int ct) {
        const char* gsrc = Ychunk + (size_t)ct * 16384;
        #pragma unroll
        for (int i = 0; i < 4; i++)
            gload_lds16(gsrc + wid * 4096 + i * 1024 + lane * 16,
                        lds + b * 16384 + ((wid * 256 + i * 64) << 4));
    };

    const char* rbase = lds + lane * 16;

    stage(0, 0);
    __syncthreads();
    int cur = 0;
    for (int ct = 0; ct < NTILES; ct++) {
        if (ct + 1 < NTILES) stage(cur ^ 1, ct + 1);   // prefetch next tile
        const char* tb = rbase + cur * 16384;
        #pragma unroll
        for (int G = 0; G < 2; G++) {                  // two 32-col groups
            f32x16 cacc;
            #pragma unroll
            for (int q = 0; q < 16; q++) cacc[q] = 0.f;
            #pragma unroll
            for (int s = 0; s < 8; s++) {
                bf16x8 bfrag = *reinterpret_cast<const bf16x8*>(tb + G * 8192 + s * 1024);
                cacc = __builtin_amdgcn_mfma_f32_32x32x16_bf16(afrag[s], bfrag, cacc, 0, 0, 0);
            }
            // sim = dot/TEMP = 2*dot ; e1 = exp(sim); e1^2 = exp(2*sim)
            #pragma unroll
            for (int q = 0; q < 16; q++) {
                float e1 = __expf(2.0f * cacc[q]);
                acc1[q] += e1;
                acc2[q] = fmaf(e1, e1, acc2[q]);
            }
        }
        __syncthreads();
        cur ^= 1;
    }

    // Reduce over the 32 lanes sharing each output row
    #pragma unroll
    for (int q = 0; q < 16; q++) {
        float a1 = acc1[q], a2 = acc2[q];
        #pragma unroll
        for (int m = 1; m < 32; m <<= 1) {
            a1 += __shfl_xor(a1, m);
            a2 += __shfl_xor(a2, m);
        }
        acc1[q] = a1; acc2[q] = a2;
    }
    if (r == 0) {
        // C/D layout: col = lane&31, row = (q&3) + 8*(q>>2) + 4*(lane>>5)
        #pragma unroll
        for (int q = 0; q < 16; q++) {
            int grow = xrow0 + (q & 3) + 8 * (q >> 2) + 4 * h;
            atomicAdd(&S1[job * BN + grow], acc1[q]);
            atomicAdd(&S2[job * BN + grow], acc2[q]);
        }
    }
}

// ---------------- finalize: per-row loss terms -> weighted mean --------------
__global__ __launch_bounds__(256) void finalize_kernel(
    const float* __restrict__ S1, const float* __restrict__ S2,
    const float* __restrict__ d1, const float* __restrict__ d2,
    const float* __restrict__ d3, float* __restrict__ out)
{
    int idx = blockIdx.x * 256 + threadIdx.x;   // 0..16383
    float term = 0.f;
    const float EM2 = 0.13533528323661270f;     // e^-2
    if (idx < 8192) {                           // inter jobs 0/1
        int j = idx >> 12, i = idx & 4095;
        float dv = j ? d2[i] : d1[i];
        float n = 4095.f;
        float pos = __expf(2.f * dv);
        float s1 = S1[j * BN + i] - pos;
        float s2 = S2[j * BN + i] - pos * pos;
        float rw = s2 * n / s1;
        float ng = (-0.1f * n * pos + rw) * (1.f / 0.9f);
        ng = fmaxf(ng, n * EM2);
        term = logf((pos + ng) / pos) * (0.5f / 4096.f);
    } else {                                    // intra rows 0..8191
        int i = idx - 8192;
        int ii = i & 4095;
        int job = 2 + (i >> 12);
        float n = 8190.f;
        const float E2 = 7.3890560989306495f, E4 = 54.598150033144236f;
        float pos = __expf(2.f * d3[ii]);
        float s1 = S1[job * BN + ii] - E2 - pos;
        float s2 = S2[job * BN + ii] - E4 - pos * pos;
        float rw = s2 * n / s1;
        float ng = (-0.1f * n * pos + rw) * (1.f / 0.9f);
        ng = fmaxf(ng, n * EM2);
        term = logf((pos + ng) / pos) * (1.f / 8192.f);
    }

    #pragma unroll
    for (int m = 1; m < 64; m <<= 1) term += __shfl_xor(term, m);
    __shared__ float sm[4];
    int wid = threadIdx.x >> 6;
    if ((threadIdx.x & 63) == 0) sm[wid] = term;
    __syncthreads();
    if (threadIdx.x == 0) atomicAdd(out, sm[0] + sm[1] + sm[2] + sm[3]);
}

extern "C" void kernel_launch(void* const* d_in, const int* in_sizes, int n_in,
                              void* d_out, int out_size, void* d_ws, size_t ws_size,
                              hipStream_t stream)
{
    const float* z1   = (const float*)d_in[0];
    const float* z2   = (const float*)d_in[1];
    // d_in[2] = text_z : unused by the reference
    const float* attr = (const float*)d_in[3];
    const int*   uni  = (const int*)d_in[4];
    float* out = (float*)d_out;

    char* ws = (char*)d_ws;
    size_t matb = (size_t)BN * DD * 2;               // bytes per bf16 matrix
    char* Z1f = ws;
    char* Z2f = Z1f + matb;
    char* G1f = Z2f + matb;
    char* G2f = G1f + matb;
    char* Af  = G2f + matb;
    float* S1 = (float*)(ws + 5 * matb);
    float* S2 = S1 + 4 * BN;
    float* d1 = S2 + 4 * BN;
    float* d2 = d1 + BN;
    float* d3 = d2 + BN;

    prep_kernel<<<128, 256, 0, stream>>>(z1, z2, attr, uni,
                                         Z1f, Z2f, G1f, G2f, Af,
                                         d1, d2, d3, S1, S2, out);
    rowsum_kernel<<<dim3(32, 24), 256, 0, stream>>>(Z1f, Z2f, G1f, G2f, Af, S1, S2);
    finalize_kernel<<<64, 256, 0, stream>>>(S1, S2, d1, d2, d3, out);
}

// Round 6
// 51.708 us; speedup vs baseline: 2.1393x; 1.0117x over previous
//
#include <hip/hip_runtime.h>
#include <hip/hip_bf16.h>

#define BN 4096
#define DD 128
#define NTILES 8   // 8 tiles x 64 cols = 512-col chunk per block

// All five bf16 matrices are pre-scaled by SQS = sqrt(2*log2(e)), so the
// MFMA dot product is directly the exp2 argument: 2^(SQS^2 * dot) = e^(2*dot).
#define SQS 1.69864356f

typedef __bf16 bf16x8 __attribute__((ext_vector_type(8)));
typedef float f32x16 __attribute__((ext_vector_type(16)));

__device__ __forceinline__ void gload_lds16(const void* g, void* l) {
    __builtin_amdgcn_global_load_lds(
        (const __attribute__((address_space(1))) void*)g,
        (__attribute__((address_space(3))) void*)l, 16, 0, 0);
}

__device__ __forceinline__ float fast_exp2(float x) {
#if __has_builtin(__builtin_amdgcn_exp2f)
    return __builtin_amdgcn_exp2f(x);
#else
    return __builtin_exp2f(x);
#endif
}

// ---------------- prep: f32 -> bf16 fragment-major (+gather), diag dots -----
// Fragment-major: per 32-row panel (8192 B), granule g = s*64 + h*32 + r
// holds row r, elements [16s+8h, 16s+8h+8). This makes BOTH the rowsum
// staging source (identity/linear) and the ds_read (lane*16 + imm) trivial.
// 256 blocks x 16 rows each (half-panel per block).
__global__ __launch_bounds__(256) void prep_kernel(
    const float* __restrict__ z1, const float* __restrict__ z2,
    const float* __restrict__ attr, const int* __restrict__ uni,
    char* __restrict__ Z1f, char* __restrict__ Z2f,
    char* __restrict__ G1f, char* __restrict__ G2f, char* __restrict__ Af,
    float* __restrict__ d1, float* __restrict__ d2, float* __restrict__ d3,
    float* __restrict__ S1, float* __restrict__ S2, float* __restrict__ out)
{
    int p = blockIdx.x;        // half-panel 0..255 (16 rows each)
    int t = threadIdx.x;       // 0..255
    int gid = p * 256 + t;
    if (gid < 4 * BN) { S1[gid] = 0.f; S2[gid] = 0.f; }
    if (gid == 0) out[0] = 0.f;

    int r = t >> 4, q = t & 15;        // row-in-block (16), col-eighth (8 f32)
    int grow = p * 16 + r;
    int arow = uni[grow];

    __shared__ __hip_bfloat16 lp[5][16][128];

    const float* sp[5] = { z1 + (size_t)grow * DD, z2 + (size_t)grow * DD,
                           z1 + (size_t)arow * DD, z2 + (size_t)arow * DD,
                           attr + (size_t)arow * DD };
    float v[5][8];
    #pragma unroll
    for (int m = 0; m < 5; m++) {
        const float4* s4 = (const float4*)(sp[m] + q * 8);
        #pragma unroll
        for (int i = 0; i < 2; i++) {
            float4 f = s4[i];
            v[m][4*i+0] = f.x; v[m][4*i+1] = f.y;
            v[m][4*i+2] = f.z; v[m][4*i+3] = f.w;
        }
    }
    float p1 = 0.f, p2 = 0.f, p3 = 0.f;
    #pragma unroll
    for (int e = 0; e < 8; e++) {
        p3 += v[0][e] * v[1][e];
        p1 += v[2][e] * v[4][e];
        p2 += v[3][e] * v[4][e];
    }
    #pragma unroll
    for (int m = 1; m < 16; m <<= 1) {
        p1 += __shfl_xor(p1, m);
        p2 += __shfl_xor(p2, m);
        p3 += __shfl_xor(p3, m);
    }
    if (q == 0) { d1[grow] = p1; d2[grow] = p2; d3[grow] = p3; }

    #pragma unroll
    for (int m = 0; m < 5; m++)
        #pragma unroll
        for (int e = 0; e < 8; e++)
            lp[m][r][q * 8 + e] = __float2bfloat16(v[m][e] * SQS);
    __syncthreads();

    // Write phase: this block's 16 rows have rr = lo..lo+15 inside panel p>>1.
    int panel = p >> 1, lo = (p & 1) * 16;
    char* dsts[5] = { Z1f, Z2f, G1f, G2f, Af };
    int s = t >> 5, h = (t >> 4) & 1, rl = t & 15;   // granule coords
    int g = s * 64 + h * 32 + lo + rl;
    #pragma unroll
    for (int m = 0; m < 5; m++) {
        bf16x8 val = *reinterpret_cast<const bf16x8*>(&lp[m][rl][s * 16 + h * 8]);
        *reinterpret_cast<bf16x8*>(dsts[m] + (size_t)panel * 8192 + (size_t)g * 16) = val;
    }
}

// ---------------- rowsum: fused sim + exp row-sum over 4 jobs ----------------
// job 0: X=G1f vs Y=Af        chunks  0..7
// job 1: X=G2f vs Y=Af        chunks  8..15
// job 2: X=Z1f vs Y={Z1f,Z2f} chunks 16..31
// job 3: X=Z2f vs Y={Z1f,Z2f} chunks 32..47
// All buffers fragment-major. Staging: identity offsets (coalesced 1KB/inst).
// Reads: ds_read_b128 at lane*16 + imm (conflict-free, no addr VALU).
// launch_bounds(256,4): VGPR cap 128 (usage ~64+AGPR; (256,5)'s cap 102
// caused scratch spill in rounds 3/4 -- WRITE_SIZE is the tripwire).
__global__ __launch_bounds__(256, 4) void rowsum_kernel(
    const char* __restrict__ Z1f, const char* __restrict__ Z2f,
    const char* __restrict__ G1f, const char* __restrict__ G2f,
    const char* __restrict__ Af,
    float* __restrict__ S1, float* __restrict__ S2)
{
    int rowblk = blockIdx.x;   // 0..31 : 128 X-rows each
    int chunk  = blockIdx.y;   // 0..47 : 512 Y-rows each

    int job;
    const char *X, *Y;
    int ybase;
    if (chunk < 8)       { job = 0; X = G1f; Y = Af; ybase = chunk * 512; }
    else if (chunk < 16) { job = 1; X = G2f; Y = Af; ybase = (chunk - 8) * 512; }
    else if (chunk < 32) { job = 2; X = Z1f; ybase = (chunk - 16) * 512;
                           Y = (ybase < BN) ? Z1f : Z2f; if (ybase >= BN) ybase -= BN; }
    else                 { job = 3; X = Z2f; ybase = (chunk - 32) * 512;
                           Y = (ybase < BN) ? Z1f : Z2f; if (ybase >= BN) ybase -= BN; }

    __shared__ char lds[2 * 16384];   // double-buffered 64-row Y tiles

    int tid  = threadIdx.x;
    int wid  = tid >> 6;      // 0..3
    int lane = tid & 63;
    int r = lane & 31, h = lane >> 5;

    // A fragments from fragment-major X: panel px, addr s*1024 + h*512 + r*16
    int xrow0 = rowblk * 128 + wid * 32;
    int px = rowblk * 4 + wid;
    const char* xp = X + (size_t)px * 8192 + h * 512 + r * 16;
    bf16x8 afrag[8];
    #pragma unroll
    for (int s = 0; s < 8; s++)
        afrag[s] = *reinterpret_cast<const bf16x8*>(xp + s * 1024);

    const char* Ychunk = Y + (size_t)ybase * 256;   // panel-aligned (512 rows)

    float acc1[16], acc2[16];
    #pragma unroll
    for (int q = 0; q < 16; q++) { acc1[q] = 0.f; acc2[q] = 0.f; }

    auto stage = [&](int b, int ct) {
        const char* gsrc = Ychunk + (size_t)ct * 16384;
        #pragma unroll
        for (int i = 0; i < 4; i++)
            gload_lds16(gsrc + wid * 4096 + i * 1024 + lane * 16,
                        lds + b * 16384 + ((wid * 256 + i * 64) << 4));
    };

    const char* rbase = lds + lane * 16;

    stage(0, 0);
    __syncthreads();
    int cur = 0;
    for (int ct = 0; ct < NTILES; ct++) {
        if (ct + 1 < NTILES) stage(cur ^ 1, ct + 1);   // prefetch next tile
        const char* tb = rbase + cur * 16384;
        #pragma unroll
        for (int G = 0; G < 2; G++) {                  // two 32-col groups
            f32x16 cacc;
            #pragma unroll
            for (int q = 0; q < 16; q++) cacc[q] = 0.f;
            #pragma unroll
            for (int s = 0; s < 8; s++) {
                bf16x8 bfrag = *reinterpret_cast<const bf16x8*>(tb + G * 8192 + s * 1024);
                cacc = __builtin_amdgcn_mfma_f32_32x32x16_bf16(afrag[s], bfrag, cacc, 0, 0, 0);
            }
            // inputs pre-scaled: cacc = (2*log2 e)*dot -> e1 = e^(2*dot)
            #pragma unroll
            for (int q = 0; q < 16; q++) {
                float e1 = fast_exp2(cacc[q]);
                acc1[q] += e1;
                acc2[q] = fmaf(e1, e1, acc2[q]);
            }
        }
        __syncthreads();
        cur ^= 1;
    }

    // Reduce over the 32 lanes sharing each output row
    #pragma unroll
    for (int q = 0; q < 16; q++) {
        float a1 = acc1[q], a2 = acc2[q];
        #pragma unroll
        for (int m = 1; m < 32; m <<= 1) {
            a1 += __shfl_xor(a1, m);
            a2 += __shfl_xor(a2, m);
        }
        acc1[q] = a1; acc2[q] = a2;
    }
    if (r == 0) {
        // C/D layout: col = lane&31, row = (q&3) + 8*(q>>2) + 4*(lane>>5)
        #pragma unroll
        for (int q = 0; q < 16; q++) {
            int grow = xrow0 + (q & 3) + 8 * (q >> 2) + 4 * h;
            atomicAdd(&S1[job * BN + grow], acc1[q]);
            atomicAdd(&S2[job * BN + grow], acc2[q]);
        }
    }
}

// ---------------- finalize: per-row loss terms -> weighted mean --------------
__global__ __launch_bounds__(256) void finalize_kernel(
    const float* __restrict__ S1, const float* __restrict__ S2,
    const float* __restrict__ d1, const float* __restrict__ d2,
    const float* __restrict__ d3, float* __restrict__ out)
{
    int idx = blockIdx.x * 256 + threadIdx.x;   // 0..16383
    float term = 0.f;
    const float EM2 = 0.13533528323661270f;     // e^-2
    if (idx < 8192) {                           // inter jobs 0/1
        int j = idx >> 12, i = idx & 4095;
        float dv = j ? d2[i] : d1[i];
        float n = 4095.f;
        float pos = __expf(2.f * dv);
        float s1 = S1[j * BN + i] - pos;
        float s2 = S2[j * BN + i] - pos * pos;
        float rw = s2 * n / s1;
        float ng = (-0.1f * n * pos + rw) * (1.f / 0.9f);
        ng = fmaxf(ng, n * EM2);
        term = logf((pos + ng) / pos) * (0.5f / 4096.f);
    } else {                                    // intra rows 0..8191
        int i = idx - 8192;
        int ii = i & 4095;
        int job = 2 + (i >> 12);
        float n = 8190.f;
        const float E2 = 7.3890560989306495f, E4 = 54.598150033144236f;
        float pos = __expf(2.f * d3[ii]);
        float s1 = S1[job * BN + ii] - E2 - pos;
        float s2 = S2[job * BN + ii] - E4 - pos * pos;
        float rw = s2 * n / s1;
        float ng = (-0.1f * n * pos + rw) * (1.f / 0.9f);
        ng = fmaxf(ng, n * EM2);
        term = logf((pos + ng) / pos) * (1.f / 8192.f);
    }

    #pragma unroll
    for (int m = 1; m < 64; m <<= 1) term += __shfl_xor(term, m);
    __shared__ float sm[4];
    int wid = threadIdx.x >> 6;
    if ((threadIdx.x & 63) == 0) sm[wid] = term;
    __syncthreads();
    if (threadIdx.x == 0) atomicAdd(out, sm[0] + sm[1] + sm[2] + sm[3]);
}

extern "C" void kernel_launch(void* const* d_in, const int* in_sizes, int n_in,
                              void* d_out, int out_size, void* d_ws, size_t ws_size,
                              hipStream_t stream)
{
    const float* z1   = (const float*)d_in[0];
    const float* z2   = (const float*)d_in[1];
    // d_in[2] = text_z : unused by the reference
    const float* attr = (const float*)d_in[3];
    const int*   uni  = (const int*)d_in[4];
    float* out = (float*)d_out;

    char* ws = (char*)d_ws;
    size_t matb = (size_t)BN * DD * 2;               // bytes per bf16 matrix
    char* Z1f = ws;
    char* Z2f = Z1f + matb;
    char* G1f = Z2f + matb;
    char* G2f = G1f + matb;
    char* Af  = G2f + matb;
    float* S1 = (float*)(ws + 5 * matb);
    float* S2 = S1 + 4 * BN;
    float* d1 = S2 + 4 * BN;
    float* d2 = d1 + BN;
    float* d3 = d2 + BN;

    prep_kernel<<<256, 256, 0, stream>>>(z1, z2, attr, uni,
                                         Z1f, Z2f, G1f, G2f, Af,
                                         d1, d2, d3, S1, S2, out);
    rowsum_kernel<<<dim3(32, 48), 256, 0, stream>>>(Z1f, Z2f, G1f, G2f, Af, S1, S2);
    finalize_kernel<<<64, 256, 0, stream>>>(S1, S2, d1, d2, d3, out);
}